// Round 4
// baseline (345.125 us; speedup 1.0000x reference)
//
#include <hip/hip_runtime.h>

// SoftTriple loss, MI355X. B=256, E=512, C=8192, K=10.
// FUSED normalize+gram+GEMM, round 4: Es staging DELETED (was 8-way bank
// conflict, 14 cyc/read measured; A is L2-resident). conv pre-transposes
// A into fragment order At[16][256][32] so ef loads are coalesced 1KB/wave
// global loads. LDS = 80KB (Wl only) -> 2 blocks/CU; one barrier total.
// ws layout (bytes):
//   [0, 262144)         At bf16 [16][256][32]  (k-chunked emb)
//   [262144, 8650752)   h float [256][8192]
//   [8650752, 8683520)  gram_part float[8192]
//   [8683520, 8684544)  ce_part  float[256]

typedef __bf16 bf16;
typedef bf16 bf16x8 __attribute__((ext_vector_type(8)));
typedef float f32x4 __attribute__((ext_vector_type(4)));

#define NCLASS 8192
#define KC 10
#define EDIM 512
#define BATCH 256

// ---------------- kernel 1: emb fp32 -> bf16, k-chunk transposed ----------
// At[(k>>5)][row][k&31]: thread i handles row = i>>6, chunk = i&63 (8 elems)
__global__ __launch_bounds__(256) void conv_kernel(
    const float* __restrict__ e, bf16* __restrict__ At)
{
    int i = blockIdx.x * 256 + threadIdx.x;   // 64 blocks: 16384 threads
    int row = i >> 6, chunk = i & 63;
    int k = chunk * 8;
    float4 a = ((const float4*)e)[i * 2];
    float4 b = ((const float4*)e)[i * 2 + 1];
    bf16x8 v;
    v[0] = (bf16)a.x; v[1] = (bf16)a.y; v[2] = (bf16)a.z; v[3] = (bf16)a.w;
    v[4] = (bf16)b.x; v[5] = (bf16)b.y; v[6] = (bf16)b.z; v[7] = (bf16)b.w;
    // dest elem = (k>>5)*8192 + row*32 + (k&31)
    *(bf16x8*)&At[((k >> 5) << 13) + (row << 5) + (k & 31)] = v;
}

// ---------------- kernel 2: fused normalize + gram + GEMM + k-softmax -----
// 512 threads = 8 waves, 2 blocks/CU. Phase 1: wave w owns class cb+w
// (10x512 f32 in regs): norms + gram via butterfly shuffles, normalized
// bf16 rows -> XOR-swizzled 80KB LDS Wl (conflict-free, verified r3).
// Phase 2: barrier-free K-loop, wave = all 80 rows x 32 batch cols
// (5mt x 2nt MFMA 16x16x32); ef straight from global (L2).
__global__ __launch_bounds__(512, 4) void fused_kernel(
    const float* __restrict__ fc,  // [81920][512] raw centers
    const bf16* __restrict__ At,   // [16][256][32] emb bf16
    float* __restrict__ h,         // [256][8192]
    float* __restrict__ gram_part) // [8192]
{
    __shared__ bf16 Wl[80 * EDIM]; // 80 KB, row-XOR-swizzled
    const int tid = threadIdx.x;
    const int wave = tid >> 6, lane = tid & 63;

    // ---- phase 1: class -> regs, norms, gram, swizzled LDS write ----
    const int c = blockIdx.x * 8 + wave;
    float4 ra[KC][2];              // lane holds elems [lane*8, lane*8+8)
    #pragma unroll
    for (int r = 0; r < KC; ++r) {
        const float4* rp =
            (const float4*)(fc + ((size_t)c * KC + r) * EDIM) + lane * 2;
        ra[r][0] = rp[0];
        ra[r][1] = rp[1];
    }
    float invn[KC];
    #pragma unroll
    for (int r = 0; r < KC; ++r) {
        float4 a = ra[r][0], b = ra[r][1];
        float s = a.x*a.x + a.y*a.y + a.z*a.z + a.w*a.w
                + b.x*b.x + b.y*b.y + b.z*b.z + b.w*b.w;
        #pragma unroll
        for (int off = 32; off; off >>= 1) s += __shfl_xor(s, off);
        invn[r] = 1.0f / fmaxf(sqrtf(s), 1e-12f);
    }
    float part = 0.f;
    #pragma unroll
    for (int i = 0; i < KC - 1; ++i) {
        #pragma unroll
        for (int j = i + 1; j < KC; ++j) {
            float4 ai = ra[i][0], bi = ra[i][1];
            float4 aj = ra[j][0], bj = ra[j][1];
            float s = ai.x*aj.x + ai.y*aj.y + ai.z*aj.z + ai.w*aj.w
                    + bi.x*bj.x + bi.y*bj.y + bi.z*bj.z + bi.w*bj.w;
            #pragma unroll
            for (int off = 32; off; off >>= 1) s += __shfl_xor(s, off);
            float sub = 1.0f - s * invn[i] * invn[j];
            if (sub <= 0.0f) sub = 1e-10f;
            part += sqrtf(2.0f * sub);
        }
    }
    if (lane == 0) gram_part[c] = part;

    // normalized bf16 write: row's 16B chunk lane -> slot lane^(row&7)
    #pragma unroll
    for (int r = 0; r < KC; ++r) {
        int row = wave * KC + r;          // 0..79 packed LDS row
        float inv = invn[r];
        float4 a = ra[r][0], b = ra[r][1];
        bf16x8 v;
        v[0] = (bf16)(a.x * inv); v[1] = (bf16)(a.y * inv);
        v[2] = (bf16)(a.z * inv); v[3] = (bf16)(a.w * inv);
        v[4] = (bf16)(b.x * inv); v[5] = (bf16)(b.y * inv);
        v[6] = (bf16)(b.z * inv); v[7] = (bf16)(b.w * inv);
        *(bf16x8*)&Wl[row * EDIM + ((lane ^ (row & 7)) << 3)] = v;
    }
    __syncthreads();   // publish Wl; only barrier in the kernel

    // ---- phase 2: barrier-free K-loop ----
    f32x4 acc[5][2];
    #pragma unroll
    for (int mt = 0; mt < 5; ++mt)
        #pragma unroll
        for (int nt = 0; nt < 2; ++nt)
            acc[mt][nt] = (f32x4){0.f, 0.f, 0.f, 0.f};

    const int q8 = (lane >> 4) * 8;
    const int fr = lane & 15;

    for (int kb = 0; kb < EDIM; kb += 32) {
        bf16x8 wf[5], ef[2];
        #pragma unroll
        for (int nt = 0; nt < 2; ++nt) {
            int row = wave * 32 + nt * 16 + fr;
            ef[nt] = *(const bf16x8*)
                &At[((kb >> 5) << 13) + (row << 5) + q8];
        }
        #pragma unroll
        for (int mt = 0; mt < 5; ++mt) {
            int row = mt * 16 + fr;
            wf[mt] = *(const bf16x8*)
                &Wl[row * EDIM + ((kb + q8) ^ ((row & 7) << 3))];
        }
        #pragma unroll
        for (int mt = 0; mt < 5; ++mt)
            #pragma unroll
            for (int nt = 0; nt < 2; ++nt)
                acc[mt][nt] = __builtin_amdgcn_mfma_f32_16x16x32_bf16(
                    wf[mt], ef[nt], acc[mt][nt], 0, 0, 0);
    }

    // epilogue: packed row r = 16*mt + 4*quad + reg; class c = r/10.
    const int col = lane & 15;
    const int quad = lane >> 4;
    const int cb = blockIdx.x * 8;
    #pragma unroll
    for (int nt = 0; nt < 2; ++nt) {
        int b = wave * 32 + nt * 16 + col;
        float hval[8];
        #pragma unroll
        for (int cc = 0; cc < 8; ++cc) {
            float xm = -1e30f;
            #pragma unroll
            for (int mt = 0; mt < 5; ++mt) {
                if (10 * cc + 10 > 16 * mt && 10 * cc < 16 * mt + 16) { // static
                    #pragma unroll
                    for (int rg = 0; rg < 4; ++rg) {
                        int r = 16 * mt + 4 * quad + rg;
                        if (r >= 10 * cc && r < 10 * cc + 10)          // runtime
                            xm = fmaxf(xm, acc[mt][nt][rg]);
                    }
                }
            }
            xm = fmaxf(xm, __shfl_xor(xm, 16));
            xm = fmaxf(xm, __shfl_xor(xm, 32));
            float s1 = 0.f, s2 = 0.f;
            #pragma unroll
            for (int mt = 0; mt < 5; ++mt) {
                if (10 * cc + 10 > 16 * mt && 10 * cc < 16 * mt + 16) { // static
                    #pragma unroll
                    for (int rg = 0; rg < 4; ++rg) {
                        int r = 16 * mt + 4 * quad + rg;
                        if (r >= 10 * cc && r < 10 * cc + 10) {        // runtime
                            float x = acc[mt][nt][rg];
                            float e = __expf(10.0f * (x - xm));
                            s1 += e; s2 += e * x;
                        }
                    }
                }
            }
            s1 += __shfl_xor(s1, 16); s1 += __shfl_xor(s1, 32);
            s2 += __shfl_xor(s2, 16); s2 += __shfl_xor(s2, 32);
            hval[cc] = s2 / s1;
        }
        if (quad == 0) {
            float4 v0 = {hval[0], hval[1], hval[2], hval[3]};
            float4 v1 = {hval[4], hval[5], hval[6], hval[7]};
            float4* dst = (float4*)&h[(size_t)b * NCLASS + cb];
            dst[0] = v0;
            dst[1] = v1;
        }
    }
}

// ---------------- kernel 3: cross-entropy over 8192 classes per row -------
__global__ __launch_bounds__(256) void ce_kernel(
    const float* __restrict__ h, const int* __restrict__ labels,
    float* __restrict__ ce_part)
{
    __shared__ float redm[4];
    __shared__ float reds[4];
    const int b = blockIdx.x, t = threadIdx.x;
    const int wave = t >> 6, lane = t & 63;
    const int lbl = labels[b];
    const float* hb = h + (size_t)b * NCLASS;

    float lg_cache[32];
    float mx = -1e30f;
    #pragma unroll
    for (int k = 0; k < 32; ++k) {
        int c = t + k * 256;
        float lg = 10.0f * hb[c];
        if (c == lbl) lg -= 0.1f;          // LMD * MARGIN
        lg_cache[k] = lg;
        mx = fmaxf(mx, lg);
    }
    #pragma unroll
    for (int off = 32; off; off >>= 1) mx = fmaxf(mx, __shfl_xor(mx, off));
    if (lane == 0) redm[wave] = mx;
    __syncthreads();
    mx = fmaxf(fmaxf(redm[0], redm[1]), fmaxf(redm[2], redm[3]));

    float s = 0.f;
    #pragma unroll
    for (int k = 0; k < 32; ++k) s += __expf(lg_cache[k] - mx);
    #pragma unroll
    for (int off = 32; off; off >>= 1) s += __shfl_xor(s, off);
    if (lane == 0) reds[wave] = s;
    __syncthreads();
    if (t == 0) {
        s = reds[0] + reds[1] + reds[2] + reds[3];
        float logit_l = 10.0f * (hb[lbl] - 0.01f);
        ce_part[b] = mx + logf(s) - logit_l;   // -logp[label]
    }
}

// ---------------- kernel 4: reduce partials + combine ---------------------
__global__ __launch_bounds__(256) void final_kernel(
    const float* __restrict__ gram_part, const float* __restrict__ ce_part,
    float* __restrict__ out)
{
    __shared__ float red[4];
    const int t = threadIdx.x, wave = t >> 6, lane = t & 63;
    float g = 0.f;
    #pragma unroll
    for (int i = 0; i < 32; ++i) g += gram_part[t + i * 256];
    float val = ce_part[t] * (1.0f / 256.0f)
              + g * (0.2f / 737280.0f);       // C*K*(K-1) = 737280
    #pragma unroll
    for (int off = 32; off; off >>= 1) val += __shfl_xor(val, off);
    if (lane == 0) red[wave] = val;
    __syncthreads();
    if (t == 0) out[0] = red[0] + red[1] + red[2] + red[3];
}

extern "C" void kernel_launch(void* const* d_in, const int* in_sizes, int n_in,
                              void* d_out, int out_size, void* d_ws, size_t ws_size,
                              hipStream_t stream) {
    const float* emb    = (const float*)d_in[0];   // [256][512]
    const int*   labels = (const int*)d_in[1];     // [256]
    const float* fc     = (const float*)d_in[2];   // [81920][512]
    float* out = (float*)d_out;

    char* ws = (char*)d_ws;
    bf16*  At        = (bf16*)ws;                        //    262144 B
    float* h         = (float*)(ws + 262144);            //   8388608 B
    float* gram_part = (float*)(ws + 8650752);           //     32768 B
    float* ce_part   = (float*)(ws + 8683520);           //      1024 B

    conv_kernel<<<64, 256, 0, stream>>>(emb, At);
    fused_kernel<<<NCLASS / 8, 512, 0, stream>>>(fc, At, h, gram_part);
    ce_kernel<<<BATCH, 256, 0, stream>>>(h, labels, ce_part);
    final_kernel<<<1, 256, 0, stream>>>(gram_part, ce_part, out);
}

// Round 5
// 313.954 us; speedup vs baseline: 1.0993x; 1.0993x over previous
//
#include <hip/hip_runtime.h>

// SoftTriple loss, MI355X. B=256, E=512, C=8192, K=10.
// FUSED normalize+gram+GEMM, round 5: identical structure to round 4 but
// __launch_bounds__(512,2): r4's (512,4) capped VGPRs at 64 and spilled
// ra[10][2] (80 f32/lane) to scratch -> 400+ MB spurious HBM traffic
// (WRITE_SIZE 245 MB vs h's 8 MB). (512,2) caps at 128 VGPR (r3 compiled
// the same phase-1 at 124, zero spill). LDS 80 KB -> 2 blocks/CU either way.
// ws layout (bytes):
//   [0, 262144)         At bf16 [16][256][32]  (k-chunked emb)
//   [262144, 8650752)   h float [256][8192]
//   [8650752, 8683520)  gram_part float[8192]
//   [8683520, 8684544)  ce_part  float[256]

typedef __bf16 bf16;
typedef bf16 bf16x8 __attribute__((ext_vector_type(8)));
typedef float f32x4 __attribute__((ext_vector_type(4)));

#define NCLASS 8192
#define KC 10
#define EDIM 512
#define BATCH 256

// ---------------- kernel 1: emb fp32 -> bf16, k-chunk transposed ----------
// At[(k>>5)][row][k&31]: thread i handles row = i>>6, chunk = i&63 (8 elems)
__global__ __launch_bounds__(256) void conv_kernel(
    const float* __restrict__ e, bf16* __restrict__ At)
{
    int i = blockIdx.x * 256 + threadIdx.x;   // 64 blocks: 16384 threads
    int row = i >> 6, chunk = i & 63;
    int k = chunk * 8;
    float4 a = ((const float4*)e)[i * 2];
    float4 b = ((const float4*)e)[i * 2 + 1];
    bf16x8 v;
    v[0] = (bf16)a.x; v[1] = (bf16)a.y; v[2] = (bf16)a.z; v[3] = (bf16)a.w;
    v[4] = (bf16)b.x; v[5] = (bf16)b.y; v[6] = (bf16)b.z; v[7] = (bf16)b.w;
    // dest elem = (k>>5)*8192 + row*32 + (k&31)
    *(bf16x8*)&At[((k >> 5) << 13) + (row << 5) + (k & 31)] = v;
}

// ---------------- kernel 2: fused normalize + gram + GEMM + k-softmax -----
// 512 threads = 8 waves, 2 blocks/CU (LDS-limited). Phase 1: wave w owns
// class cb+w (10x512 f32 in regs): norms + gram via butterfly shuffles,
// normalized bf16 rows -> XOR-swizzled 80KB LDS Wl (conflict-free,
// verified by r4 counter arithmetic). Phase 2: barrier-free K-loop,
// wave = all 80 rows x 32 batch cols (5mt x 2nt MFMA 16x16x32); ef
// fragments straight from global At (L2-resident).
__global__ __launch_bounds__(512, 2) void fused_kernel(
    const float* __restrict__ fc,  // [81920][512] raw centers
    const bf16* __restrict__ At,   // [16][256][32] emb bf16
    float* __restrict__ h,         // [256][8192]
    float* __restrict__ gram_part) // [8192]
{
    __shared__ bf16 Wl[80 * EDIM]; // 80 KB, row-XOR-swizzled
    const int tid = threadIdx.x;
    const int wave = tid >> 6, lane = tid & 63;

    // ---- phase 1: class -> regs, norms, gram, swizzled LDS write ----
    const int c = blockIdx.x * 8 + wave;
    float4 ra[KC][2];              // lane holds elems [lane*8, lane*8+8)
    #pragma unroll
    for (int r = 0; r < KC; ++r) {
        const float4* rp =
            (const float4*)(fc + ((size_t)c * KC + r) * EDIM) + lane * 2;
        ra[r][0] = rp[0];
        ra[r][1] = rp[1];
    }
    float invn[KC];
    #pragma unroll
    for (int r = 0; r < KC; ++r) {
        float4 a = ra[r][0], b = ra[r][1];
        float s = a.x*a.x + a.y*a.y + a.z*a.z + a.w*a.w
                + b.x*b.x + b.y*b.y + b.z*b.z + b.w*b.w;
        #pragma unroll
        for (int off = 32; off; off >>= 1) s += __shfl_xor(s, off);
        invn[r] = 1.0f / fmaxf(sqrtf(s), 1e-12f);
    }
    float part = 0.f;
    #pragma unroll
    for (int i = 0; i < KC - 1; ++i) {
        #pragma unroll
        for (int j = i + 1; j < KC; ++j) {
            float4 ai = ra[i][0], bi = ra[i][1];
            float4 aj = ra[j][0], bj = ra[j][1];
            float s = ai.x*aj.x + ai.y*aj.y + ai.z*aj.z + ai.w*aj.w
                    + bi.x*bj.x + bi.y*bj.y + bi.z*bj.z + bi.w*bj.w;
            #pragma unroll
            for (int off = 32; off; off >>= 1) s += __shfl_xor(s, off);
            float sub = 1.0f - s * invn[i] * invn[j];
            if (sub <= 0.0f) sub = 1e-10f;
            part += sqrtf(2.0f * sub);
        }
    }
    if (lane == 0) gram_part[c] = part;

    // normalized bf16 write: row's 16B chunk lane -> slot lane^(row&7)
    #pragma unroll
    for (int r = 0; r < KC; ++r) {
        int row = wave * KC + r;          // 0..79 packed LDS row
        float inv = invn[r];
        float4 a = ra[r][0], b = ra[r][1];
        bf16x8 v;
        v[0] = (bf16)(a.x * inv); v[1] = (bf16)(a.y * inv);
        v[2] = (bf16)(a.z * inv); v[3] = (bf16)(a.w * inv);
        v[4] = (bf16)(b.x * inv); v[5] = (bf16)(b.y * inv);
        v[6] = (bf16)(b.z * inv); v[7] = (bf16)(b.w * inv);
        *(bf16x8*)&Wl[row * EDIM + ((lane ^ (row & 7)) << 3)] = v;
    }
    __syncthreads();   // publish Wl; only barrier in the kernel

    // ---- phase 2: barrier-free K-loop ----
    f32x4 acc[5][2];
    #pragma unroll
    for (int mt = 0; mt < 5; ++mt)
        #pragma unroll
        for (int nt = 0; nt < 2; ++nt)
            acc[mt][nt] = (f32x4){0.f, 0.f, 0.f, 0.f};

    const int q8 = (lane >> 4) * 8;
    const int fr = lane & 15;

    for (int kb = 0; kb < EDIM; kb += 32) {
        bf16x8 wf[5], ef[2];
        #pragma unroll
        for (int nt = 0; nt < 2; ++nt) {
            int row = wave * 32 + nt * 16 + fr;
            ef[nt] = *(const bf16x8*)
                &At[((kb >> 5) << 13) + (row << 5) + q8];
        }
        #pragma unroll
        for (int mt = 0; mt < 5; ++mt) {
            int row = mt * 16 + fr;
            wf[mt] = *(const bf16x8*)
                &Wl[row * EDIM + ((kb + q8) ^ ((row & 7) << 3))];
        }
        #pragma unroll
        for (int mt = 0; mt < 5; ++mt)
            #pragma unroll
            for (int nt = 0; nt < 2; ++nt)
                acc[mt][nt] = __builtin_amdgcn_mfma_f32_16x16x32_bf16(
                    wf[mt], ef[nt], acc[mt][nt], 0, 0, 0);
    }

    // epilogue: packed row r = 16*mt + 4*quad + reg; class c = r/10.
    const int col = lane & 15;
    const int quad = lane >> 4;
    const int cb = blockIdx.x * 8;
    #pragma unroll
    for (int nt = 0; nt < 2; ++nt) {
        int b = wave * 32 + nt * 16 + col;
        float hval[8];
        #pragma unroll
        for (int cc = 0; cc < 8; ++cc) {
            float xm = -1e30f;
            #pragma unroll
            for (int mt = 0; mt < 5; ++mt) {
                if (10 * cc + 10 > 16 * mt && 10 * cc < 16 * mt + 16) { // static
                    #pragma unroll
                    for (int rg = 0; rg < 4; ++rg) {
                        int r = 16 * mt + 4 * quad + rg;
                        if (r >= 10 * cc && r < 10 * cc + 10)          // runtime
                            xm = fmaxf(xm, acc[mt][nt][rg]);
                    }
                }
            }
            xm = fmaxf(xm, __shfl_xor(xm, 16));
            xm = fmaxf(xm, __shfl_xor(xm, 32));
            float s1 = 0.f, s2 = 0.f;
            #pragma unroll
            for (int mt = 0; mt < 5; ++mt) {
                if (10 * cc + 10 > 16 * mt && 10 * cc < 16 * mt + 16) { // static
                    #pragma unroll
                    for (int rg = 0; rg < 4; ++rg) {
                        int r = 16 * mt + 4 * quad + rg;
                        if (r >= 10 * cc && r < 10 * cc + 10) {        // runtime
                            float x = acc[mt][nt][rg];
                            float e = __expf(10.0f * (x - xm));
                            s1 += e; s2 += e * x;
                        }
                    }
                }
            }
            s1 += __shfl_xor(s1, 16); s1 += __shfl_xor(s1, 32);
            s2 += __shfl_xor(s2, 16); s2 += __shfl_xor(s2, 32);
            hval[cc] = s2 / s1;
        }
        if (quad == 0) {
            float4 v0 = {hval[0], hval[1], hval[2], hval[3]};
            float4 v1 = {hval[4], hval[5], hval[6], hval[7]};
            float4* dst = (float4*)&h[(size_t)b * NCLASS + cb];
            dst[0] = v0;
            dst[1] = v1;
        }
    }
}

// ---------------- kernel 3: cross-entropy over 8192 classes per row -------
__global__ __launch_bounds__(256) void ce_kernel(
    const float* __restrict__ h, const int* __restrict__ labels,
    float* __restrict__ ce_part)
{
    __shared__ float redm[4];
    __shared__ float reds[4];
    const int b = blockIdx.x, t = threadIdx.x;
    const int wave = t >> 6, lane = t & 63;
    const int lbl = labels[b];
    const float* hb = h + (size_t)b * NCLASS;

    float lg_cache[32];
    float mx = -1e30f;
    #pragma unroll
    for (int k = 0; k < 32; ++k) {
        int c = t + k * 256;
        float lg = 10.0f * hb[c];
        if (c == lbl) lg -= 0.1f;          // LMD * MARGIN
        lg_cache[k] = lg;
        mx = fmaxf(mx, lg);
    }
    #pragma unroll
    for (int off = 32; off; off >>= 1) mx = fmaxf(mx, __shfl_xor(mx, off));
    if (lane == 0) redm[wave] = mx;
    __syncthreads();
    mx = fmaxf(fmaxf(redm[0], redm[1]), fmaxf(redm[2], redm[3]));

    float s = 0.f;
    #pragma unroll
    for (int k = 0; k < 32; ++k) s += __expf(lg_cache[k] - mx);
    #pragma unroll
    for (int off = 32; off; off >>= 1) s += __shfl_xor(s, off);
    if (lane == 0) reds[wave] = s;
    __syncthreads();
    if (t == 0) {
        s = reds[0] + reds[1] + reds[2] + reds[3];
        float logit_l = 10.0f * (hb[lbl] - 0.01f);
        ce_part[b] = mx + logf(s) - logit_l;   // -logp[label]
    }
}

// ---------------- kernel 4: reduce partials + combine ---------------------
__global__ __launch_bounds__(256) void final_kernel(
    const float* __restrict__ gram_part, const float* __restrict__ ce_part,
    float* __restrict__ out)
{
    __shared__ float red[4];
    const int t = threadIdx.x, wave = t >> 6, lane = t & 63;
    float g = 0.f;
    #pragma unroll
    for (int i = 0; i < 32; ++i) g += gram_part[t + i * 256];
    float val = ce_part[t] * (1.0f / 256.0f)
              + g * (0.2f / 737280.0f);       // C*K*(K-1) = 737280
    #pragma unroll
    for (int off = 32; off; off >>= 1) val += __shfl_xor(val, off);
    if (lane == 0) red[wave] = val;
    __syncthreads();
    if (t == 0) out[0] = red[0] + red[1] + red[2] + red[3];
}

extern "C" void kernel_launch(void* const* d_in, const int* in_sizes, int n_in,
                              void* d_out, int out_size, void* d_ws, size_t ws_size,
                              hipStream_t stream) {
    const float* emb    = (const float*)d_in[0];   // [256][512]
    const int*   labels = (const int*)d_in[1];     // [256]
    const float* fc     = (const float*)d_in[2];   // [81920][512]
    float* out = (float*)d_out;

    char* ws = (char*)d_ws;
    bf16*  At        = (bf16*)ws;                        //    262144 B
    float* h         = (float*)(ws + 262144);            //   8388608 B
    float* gram_part = (float*)(ws + 8650752);           //     32768 B
    float* ce_part   = (float*)(ws + 8683520);           //      1024 B

    conv_kernel<<<64, 256, 0, stream>>>(emb, At);
    fused_kernel<<<NCLASS / 8, 512, 0, stream>>>(fc, At, h, gram_part);
    ce_kernel<<<BATCH, 256, 0, stream>>>(h, labels, ce_part);
    final_kernel<<<1, 256, 0, stream>>>(gram_part, ce_part, out);
}

// Round 6
// 302.276 us; speedup vs baseline: 1.1418x; 1.0386x over previous
//
#include <hip/hip_runtime.h>

// SoftTriple loss, MI355X. B=256, E=512, C=8192, K=10.
// Round 6: back to the split pipeline (best measured, r2) with the GEMM's
// two measured inefficiencies fixed:
//  - Es staging deleted: ef fragments read from fragment-ordered At in
//    global (L2-resident, 256 KB). r3 counters: Es reads cost 14 cyc extra
//    each (8-way bank conflict).
//  - Ws fragment reads de-conflicted: chunk slot = q ^ ((row>>1)&3)
//    (2-way per 16-lane phase = free, m136). global_load_lds writes LDS
//    linearly, so the global SOURCE chunk is pre-permuted with the same
//    XOR involution (both-sides-or-neither).
// ws layout (bytes):
//   [0, 83886080)        w  bf16 [81920][512]  (normalized, compact)
//   [83886080, 84148224) At bf16 [16][256][32] (k-chunked emb)
//   [84148352, 92536960) h float [256][8192]
//   [92536960, 92569728) gram_part float[8192]
//   [92569728, 92570752) ce_part  float[256]

typedef __bf16 bf16;
typedef bf16 bf16x8 __attribute__((ext_vector_type(8)));
typedef float f32x4 __attribute__((ext_vector_type(4)));

#define NCLASS 8192
#define KC 10
#define EDIM 512
#define BATCH 256

__device__ inline void load_lds16(const void* g, void* l) {
    __builtin_amdgcn_global_load_lds(
        (const __attribute__((address_space(1))) void*)g,
        (__attribute__((address_space(3))) void*)l, 16, 0, 0);
}

// ---------------- kernel 1: normalize + gram + compact bf16 write ---------
// Verified r2 kernel, unchanged.
__global__ __launch_bounds__(256) void prep_kernel(
    const float* __restrict__ fc, bf16* __restrict__ w,
    float* __restrict__ gram_part)
{
    __shared__ float rows[KC * EDIM];   // 20 KB
    __shared__ float s_invn[KC];
    __shared__ float s_wsum[4];
    const int c = blockIdx.x;
    const int t = threadIdx.x;
    const int wave = t >> 6, lane = t & 63;

    const float4* src = (const float4*)(fc + (size_t)c * (KC * EDIM));
    float4* rows4 = (float4*)rows;
    #pragma unroll
    for (int i = 0; i < 5; ++i) rows4[t + i * 256] = src[t + i * 256];
    __syncthreads();

    for (int r = wave; r < KC; r += 4) {
        float s = 0.f;
        #pragma unroll
        for (int j = 0; j < 8; ++j) {
            float v = rows[r * EDIM + lane + j * 64];
            s += v * v;
        }
        #pragma unroll
        for (int off = 32; off; off >>= 1) s += __shfl_xor(s, off);
        if (lane == 0) s_invn[r] = 1.0f / fmaxf(sqrtf(s), 1e-12f);
    }
    __syncthreads();

    bf16x8* dst = (bf16x8*)(w + (size_t)c * (KC * EDIM));
    #pragma unroll
    for (int p = 0; p < 3; ++p) {
        int j = t + p * 256;
        if (j < 640) {
            int r = j >> 6;
            float inv = s_invn[r];
            float4 a = *(const float4*)(rows + j * 8);
            float4 b = *(const float4*)(rows + j * 8 + 4);
            bf16x8 v;
            v[0] = (bf16)(a.x * inv); v[1] = (bf16)(a.y * inv);
            v[2] = (bf16)(a.z * inv); v[3] = (bf16)(a.w * inv);
            v[4] = (bf16)(b.x * inv); v[5] = (bf16)(b.y * inv);
            v[6] = (bf16)(b.z * inv); v[7] = (bf16)(b.w * inv);
            dst[j] = v;
        }
    }

    float part = 0.f;
    for (int p = wave; p < 45; p += 4) {
        int i = 0, pp = p;
        while (pp >= 9 - i) { pp -= 9 - i; ++i; }
        int j = i + 1 + pp;
        float s = 0.f;
        #pragma unroll
        for (int u = 0; u < 8; ++u)
            s += rows[i * EDIM + lane + u * 64] * rows[j * EDIM + lane + u * 64];
        #pragma unroll
        for (int off = 32; off; off >>= 1) s += __shfl_xor(s, off);
        if (lane == 0) {
            float sub = 1.0f - s * s_invn[i] * s_invn[j];
            if (sub <= 0.0f) sub = 1e-10f;
            part += sqrtf(2.0f * sub);
        }
    }
    if (lane == 0) s_wsum[wave] = part;
    __syncthreads();
    if (t == 0) gram_part[c] = s_wsum[0] + s_wsum[1] + s_wsum[2] + s_wsum[3];
}

// ---------------- kernel 1b: emb fp32 -> bf16, k-chunk transposed ---------
// At[(k>>5)][row][k&31] (verified r4/r5).
__global__ __launch_bounds__(256) void conv_kernel(
    const float* __restrict__ e, bf16* __restrict__ At)
{
    int i = blockIdx.x * 256 + threadIdx.x;
    int row = i >> 6, chunk = i & 63;
    int k = chunk * 8;
    float4 a = ((const float4*)e)[i * 2];
    float4 b = ((const float4*)e)[i * 2 + 1];
    bf16x8 v;
    v[0] = (bf16)a.x; v[1] = (bf16)a.y; v[2] = (bf16)a.z; v[3] = (bf16)a.w;
    v[4] = (bf16)b.x; v[5] = (bf16)b.y; v[6] = (bf16)b.z; v[7] = (bf16)b.w;
    *(bf16x8*)&At[((k >> 5) << 13) + (row << 5) + (k & 31)] = v;
}

// ---------------- kernel 2: GEMM (81920 x 256 x 512) + softmax-K epilogue
// PACKED M: BM=80 rows = 8 whole classes per block. 512 threads = 8 waves,
// wave grid 1(m) x 8(n): each wave = 80 rows x 32 batch cols (5mt x 2nt
// MFMA 16x16x32). Per K-step: waves 0..4 stage the 80x32 W-subtile via
// global_load_lds (linear dest, source chunk pre-swizzled); ef from At
// global. Epilogue verified in r2 (absmax 0).
__global__ __launch_bounds__(512, 2) void gemm_h_kernel(
    const bf16* __restrict__ W,    // [81920][512] compact normalized centers
    const bf16* __restrict__ At,   // [16][256][32] emb bf16
    float* __restrict__ h)         // [256][8192]
{
    __shared__ bf16 Ws[80 * 32];   // 5 KB, chunk-swizzled
    const int tid = threadIdx.x;
    const int wave = tid >> 6, lane = tid & 63;

    f32x4 acc[5][2];
    #pragma unroll
    for (int mt = 0; mt < 5; ++mt)
        #pragma unroll
        for (int nt = 0; nt < 2; ++nt)
            acc[mt][nt] = (f32x4){0.f, 0.f, 0.f, 0.f};

    const size_t g0 = (size_t)blockIdx.x * 80;   // first packed W row

    // staging geometry: chunk j = tid (j<320); LDS slot j is linear.
    // LDS slot (row, s) holds global chunk gc = s ^ ((row>>1)&3).
    const int srow = tid >> 2;                   // 0..79 (tid<320)
    const int gc = (tid & 3) ^ ((srow >> 1) & 3);
    const bf16* wsrc = W + (g0 + srow) * EDIM + gc * 8;

    const int q = lane >> 4;        // fragment chunk 0..3
    const int q8 = q * 8;
    const int fr = lane & 15;

    for (int kb = 0; kb < EDIM; kb += 32) {
        if (tid < 320)
            load_lds16(wsrc + kb, Ws + wave * 64 * 8);
        __syncthreads();

        bf16x8 wf[5], ef[2];
        #pragma unroll
        for (int nt = 0; nt < 2; ++nt) {
            int row = wave * 32 + nt * 16 + fr;
            ef[nt] = *(const bf16x8*)
                &At[((kb >> 5) << 13) + (row << 5) + q8];
        }
        #pragma unroll
        for (int mt = 0; mt < 5; ++mt) {
            int row = mt * 16 + fr;
            int slot = q ^ ((row >> 1) & 3);
            wf[mt] = *(const bf16x8*)&Ws[row * 32 + slot * 8];
        }
        #pragma unroll
        for (int mt = 0; mt < 5; ++mt)
            #pragma unroll
            for (int nt = 0; nt < 2; ++nt)
                acc[mt][nt] = __builtin_amdgcn_mfma_f32_16x16x32_bf16(
                    wf[mt], ef[nt], acc[mt][nt], 0, 0, 0);
        __syncthreads();
    }

    // epilogue: packed row r = 16*mt + 4*quad + reg; class c = r/10.
    const int col = lane & 15;
    const int quad = lane >> 4;
    const int cb = blockIdx.x * 8;
    #pragma unroll
    for (int nt = 0; nt < 2; ++nt) {
        int b = wave * 32 + nt * 16 + col;
        float hval[8];
        #pragma unroll
        for (int cc = 0; cc < 8; ++cc) {
            float xm = -1e30f;
            #pragma unroll
            for (int mt = 0; mt < 5; ++mt) {
                if (10 * cc + 10 > 16 * mt && 10 * cc < 16 * mt + 16) { // static
                    #pragma unroll
                    for (int rg = 0; rg < 4; ++rg) {
                        int r = 16 * mt + 4 * quad + rg;
                        if (r >= 10 * cc && r < 10 * cc + 10)          // runtime
                            xm = fmaxf(xm, acc[mt][nt][rg]);
                    }
                }
            }
            xm = fmaxf(xm, __shfl_xor(xm, 16));
            xm = fmaxf(xm, __shfl_xor(xm, 32));
            float s1 = 0.f, s2 = 0.f;
            #pragma unroll
            for (int mt = 0; mt < 5; ++mt) {
                if (10 * cc + 10 > 16 * mt && 10 * cc < 16 * mt + 16) { // static
                    #pragma unroll
                    for (int rg = 0; rg < 4; ++rg) {
                        int r = 16 * mt + 4 * quad + rg;
                        if (r >= 10 * cc && r < 10 * cc + 10) {        // runtime
                            float x = acc[mt][nt][rg];
                            float e = __expf(10.0f * (x - xm));
                            s1 += e; s2 += e * x;
                        }
                    }
                }
            }
            s1 += __shfl_xor(s1, 16); s1 += __shfl_xor(s1, 32);
            s2 += __shfl_xor(s2, 16); s2 += __shfl_xor(s2, 32);
            hval[cc] = s2 / s1;
        }
        if (quad == 0) {
            float4 v0 = {hval[0], hval[1], hval[2], hval[3]};
            float4 v1 = {hval[4], hval[5], hval[6], hval[7]};
            float4* dst = (float4*)&h[(size_t)b * NCLASS + cb];
            dst[0] = v0;
            dst[1] = v1;
        }
    }
}

// ---------------- kernel 3: cross-entropy over 8192 classes per row -------
__global__ __launch_bounds__(256) void ce_kernel(
    const float* __restrict__ h, const int* __restrict__ labels,
    float* __restrict__ ce_part)
{
    __shared__ float redm[4];
    __shared__ float reds[4];
    const int b = blockIdx.x, t = threadIdx.x;
    const int wave = t >> 6, lane = t & 63;
    const int lbl = labels[b];
    const float* hb = h + (size_t)b * NCLASS;

    float lg_cache[32];
    float mx = -1e30f;
    #pragma unroll
    for (int k = 0; k < 32; ++k) {
        int c = t + k * 256;
        float lg = 10.0f * hb[c];
        if (c == lbl) lg -= 0.1f;          // LMD * MARGIN
        lg_cache[k] = lg;
        mx = fmaxf(mx, lg);
    }
    #pragma unroll
    for (int off = 32; off; off >>= 1) mx = fmaxf(mx, __shfl_xor(mx, off));
    if (lane == 0) redm[wave] = mx;
    __syncthreads();
    mx = fmaxf(fmaxf(redm[0], redm[1]), fmaxf(redm[2], redm[3]));

    float s = 0.f;
    #pragma unroll
    for (int k = 0; k < 32; ++k) s += __expf(lg_cache[k] - mx);
    #pragma unroll
    for (int off = 32; off; off >>= 1) s += __shfl_xor(s, off);
    if (lane == 0) reds[wave] = s;
    __syncthreads();
    if (t == 0) {
        s = reds[0] + reds[1] + reds[2] + reds[3];
        float logit_l = 10.0f * (hb[lbl] - 0.01f);
        ce_part[b] = mx + logf(s) - logit_l;   // -logp[label]
    }
}

// ---------------- kernel 4: reduce partials + combine ---------------------
__global__ __launch_bounds__(256) void final_kernel(
    const float* __restrict__ gram_part, const float* __restrict__ ce_part,
    float* __restrict__ out)
{
    __shared__ float red[4];
    const int t = threadIdx.x, wave = t >> 6, lane = t & 63;
    float g = 0.f;
    #pragma unroll
    for (int i = 0; i < 32; ++i) g += gram_part[t + i * 256];
    float val = ce_part[t] * (1.0f / 256.0f)
              + g * (0.2f / 737280.0f);       // C*K*(K-1) = 737280
    #pragma unroll
    for (int off = 32; off; off >>= 1) val += __shfl_xor(val, off);
    if (lane == 0) red[wave] = val;
    __syncthreads();
    if (t == 0) out[0] = red[0] + red[1] + red[2] + red[3];
}

extern "C" void kernel_launch(void* const* d_in, const int* in_sizes, int n_in,
                              void* d_out, int out_size, void* d_ws, size_t ws_size,
                              hipStream_t stream) {
    const float* emb    = (const float*)d_in[0];   // [256][512]
    const int*   labels = (const int*)d_in[1];     // [256]
    const float* fc     = (const float*)d_in[2];   // [81920][512]
    float* out = (float*)d_out;

    char* ws = (char*)d_ws;
    bf16*  w         = (bf16*)ws;                        //  83886080 B
    bf16*  At        = (bf16*)(ws + 83886080);           //    262144 B
    float* h         = (float*)(ws + 84148352);          //   8388608 B
    float* gram_part = (float*)(ws + 92536960);          //     32768 B
    float* ce_part   = (float*)(ws + 92569728);          //      1024 B

    prep_kernel<<<NCLASS, 256, 0, stream>>>(fc, w, gram_part);
    conv_kernel<<<64, 256, 0, stream>>>(emb, At);
    gemm_h_kernel<<<81920 / 80, 512, 0, stream>>>(w, At, h);
    ce_kernel<<<BATCH, 256, 0, stream>>>(h, labels, ce_part);
    final_kernel<<<1, 256, 0, stream>>>(gram_part, ce_part, out);
}

// Round 7
// 300.236 us; speedup vs baseline: 1.1495x; 1.0068x over previous
//
#include <hip/hip_runtime.h>

// SoftTriple loss, MI355X. B=256, E=512, C=8192, K=10.
// Round 7: split pipeline; GEMM K-loop restructured to minimum-2-phase
// pipelined form: BK=64, double-buffered Ws (2x10KB), ONE barrier per
// K-step (8 total vs r6's 32). Staging of tile t+1 issued BEFORE compute
// of tile t (compiler's vmcnt(0)-before-barrier then drains after compute
// has hidden the latency). LDS swizzle: slot s = cc ^ (row&7) at 128B row
// stride -> each 16-lane subpass covers all 8 bank-quads 2-way (free);
// global source chunk pre-permuted with the same involution.
// conv merged into prep grid; ce/final float4-vectorized.
// ws layout (bytes):
//   [0, 83886080)        w  bf16 [81920][512]  (normalized, compact)
//   [83886080, 84148224) At bf16 [16][256][32] (k-chunked emb)
//   [84148352, 92536960) h float [256][8192]
//   [92536960, 92569728) gram_part float[8192]
//   [92569728, 92570752) ce_part  float[256]

typedef __bf16 bf16;
typedef bf16 bf16x8 __attribute__((ext_vector_type(8)));
typedef float f32x4 __attribute__((ext_vector_type(4)));

#define NCLASS 8192
#define KC 10
#define EDIM 512
#define BATCH 256
#define BK 64

__device__ inline void load_lds16(const void* g, void* l) {
    __builtin_amdgcn_global_load_lds(
        (const __attribute__((address_space(1))) void*)g,
        (__attribute__((address_space(3))) void*)l, 16, 0, 0);
}

// ---------------- kernel 1: normalize + gram + compact bf16 write ---------
// blocks [0, 8192): prep (verified r2 code). blocks [8192, 8256): emb->At.
__global__ __launch_bounds__(256) void prep_kernel(
    const float* __restrict__ fc, bf16* __restrict__ w,
    float* __restrict__ gram_part,
    const float* __restrict__ e, bf16* __restrict__ At)
{
    __shared__ float rows[KC * EDIM];   // 20 KB
    __shared__ float s_invn[KC];
    __shared__ float s_wsum[4];
    const int t = threadIdx.x;

    if (blockIdx.x >= NCLASS) {
        // ---- emb fp32 -> bf16, k-chunk transposed: At[k>>5][row][k&31] ----
        int i = (blockIdx.x - NCLASS) * 256 + t;
        int row = i >> 6, chunk = i & 63;
        int k = chunk * 8;
        float4 a = ((const float4*)e)[i * 2];
        float4 b = ((const float4*)e)[i * 2 + 1];
        bf16x8 v;
        v[0] = (bf16)a.x; v[1] = (bf16)a.y; v[2] = (bf16)a.z; v[3] = (bf16)a.w;
        v[4] = (bf16)b.x; v[5] = (bf16)b.y; v[6] = (bf16)b.z; v[7] = (bf16)b.w;
        *(bf16x8*)&At[((k >> 5) << 13) + (row << 5) + (k & 31)] = v;
        return;
    }

    const int c = blockIdx.x;
    const int wave = t >> 6, lane = t & 63;

    const float4* src = (const float4*)(fc + (size_t)c * (KC * EDIM));
    float4* rows4 = (float4*)rows;
    #pragma unroll
    for (int i = 0; i < 5; ++i) rows4[t + i * 256] = src[t + i * 256];
    __syncthreads();

    for (int r = wave; r < KC; r += 4) {
        float s = 0.f;
        #pragma unroll
        for (int j = 0; j < 8; ++j) {
            float v = rows[r * EDIM + lane + j * 64];
            s += v * v;
        }
        #pragma unroll
        for (int off = 32; off; off >>= 1) s += __shfl_xor(s, off);
        if (lane == 0) s_invn[r] = 1.0f / fmaxf(sqrtf(s), 1e-12f);
    }
    __syncthreads();

    bf16x8* dst = (bf16x8*)(w + (size_t)c * (KC * EDIM));
    #pragma unroll
    for (int p = 0; p < 3; ++p) {
        int j = t + p * 256;
        if (j < 640) {
            int r = j >> 6;
            float inv = s_invn[r];
            float4 a = *(const float4*)(rows + j * 8);
            float4 b = *(const float4*)(rows + j * 8 + 4);
            bf16x8 v;
            v[0] = (bf16)(a.x * inv); v[1] = (bf16)(a.y * inv);
            v[2] = (bf16)(a.z * inv); v[3] = (bf16)(a.w * inv);
            v[4] = (bf16)(b.x * inv); v[5] = (bf16)(b.y * inv);
            v[6] = (bf16)(b.z * inv); v[7] = (bf16)(b.w * inv);
            dst[j] = v;
        }
    }

    float part = 0.f;
    for (int p = wave; p < 45; p += 4) {
        int i = 0, pp = p;
        while (pp >= 9 - i) { pp -= 9 - i; ++i; }
        int j = i + 1 + pp;
        float s = 0.f;
        #pragma unroll
        for (int u = 0; u < 8; ++u)
            s += rows[i * EDIM + lane + u * 64] * rows[j * EDIM + lane + u * 64];
        #pragma unroll
        for (int off = 32; off; off >>= 1) s += __shfl_xor(s, off);
        if (lane == 0) {
            float sub = 1.0f - s * s_invn[i] * s_invn[j];
            if (sub <= 0.0f) sub = 1e-10f;
            part += sqrtf(2.0f * sub);
        }
    }
    if (lane == 0) s_wsum[wave] = part;
    __syncthreads();
    if (t == 0) gram_part[c] = s_wsum[0] + s_wsum[1] + s_wsum[2] + s_wsum[3];
}

// ---------------- kernel 2: GEMM (81920 x 256 x 512) + softmax-K epilogue
// PACKED M: BM=80 rows = 8 classes/block. 512 threads = 8 waves, wave grid
// 1m x 8n: each wave = 80 rows x 32 batch cols (5mt x 2nt MFMA 16x16x32).
// BK=64 double-buffered: stage(t+1) -> compute(t) -> barrier. LDS slot
// (row, s) holds global chunk s^(row&7) (16B); fragment read slot
// cc^(row&7) -> conflict-free under 16-lane subpass model.
__global__ __launch_bounds__(512, 2) void gemm_h_kernel(
    const bf16* __restrict__ W,    // [81920][512] compact normalized centers
    const bf16* __restrict__ At,   // [16][256][32] emb bf16
    float* __restrict__ h)         // [256][8192]
{
    __shared__ bf16 Ws[2][80 * BK];   // 2 x 10 KB
    const int tid = threadIdx.x;
    const int wave = tid >> 6, lane = tid & 63;

    f32x4 acc[5][2];
    #pragma unroll
    for (int mt = 0; mt < 5; ++mt)
        #pragma unroll
        for (int nt = 0; nt < 2; ++nt)
            acc[mt][nt] = (f32x4){0.f, 0.f, 0.f, 0.f};

    const size_t g0 = (size_t)blockIdx.x * 80;   // first packed W row

    // staging: slot j in [0,640): row=j>>3, s=j&7, global chunk = s^(row&7).
    // call A: j = tid (512 slots); call B: j = 512+tid (tid<128).
    const int rA = tid >> 3, sA = tid & 7;
    const bf16* srcA = W + (g0 + rA) * EDIM + ((sA ^ (rA & 7)) << 3);
    const int rB = (512 + tid) >> 3, sB = tid & 7;
    const bf16* srcB = W + (g0 + rB) * EDIM + ((sB ^ (rB & 7)) << 3);

    const int q = lane >> 4;        // fragment chunk within 32-k
    const int q8 = q * 8;
    const int fr = lane & 15;

    // prologue: stage tile 0 into buf 0
    load_lds16(srcA, &Ws[0][wave * 512]);
    if (tid < 128) load_lds16(srcB, &Ws[0][4096 + wave * 512]);
    __syncthreads();

    for (int t = 0; t < 8; ++t) {
        const int cur = t & 1;
        if (t < 7) {
            const int kb = (t + 1) * BK;
            load_lds16(srcA + kb, &Ws[cur ^ 1][wave * 512]);
            if (tid < 128) load_lds16(srcB + kb, &Ws[cur ^ 1][4096 + wave * 512]);
        }
        #pragma unroll
        for (int kk = 0; kk < BK; kk += 32) {
            const int ccb = kk >> 3;             // 0 or 4
            bf16x8 wf[5], ef[2];
            #pragma unroll
            for (int nt = 0; nt < 2; ++nt) {
                int row = wave * 32 + nt * 16 + fr;
                ef[nt] = *(const bf16x8*)
                    &At[((t * 2 + (kk >> 5)) << 13) + (row << 5) + q8];
            }
            #pragma unroll
            for (int mt = 0; mt < 5; ++mt) {
                int row = mt * 16 + fr;
                int s = (ccb + q) ^ (row & 7);
                wf[mt] = *(const bf16x8*)&Ws[cur][row * BK + (s << 3)];
            }
            #pragma unroll
            for (int mt = 0; mt < 5; ++mt)
                #pragma unroll
                for (int nt = 0; nt < 2; ++nt)
                    acc[mt][nt] = __builtin_amdgcn_mfma_f32_16x16x32_bf16(
                        wf[mt], ef[nt], acc[mt][nt], 0, 0, 0);
        }
        __syncthreads();
    }

    // epilogue: packed row r = 16*mt + 4*quad + reg; class c = r/10.
    const int col = lane & 15;
    const int quad = lane >> 4;
    const int cb = blockIdx.x * 8;
    #pragma unroll
    for (int nt = 0; nt < 2; ++nt) {
        int b = wave * 32 + nt * 16 + col;
        float hval[8];
        #pragma unroll
        for (int cc = 0; cc < 8; ++cc) {
            float xm = -1e30f;
            #pragma unroll
            for (int mt = 0; mt < 5; ++mt) {
                if (10 * cc + 10 > 16 * mt && 10 * cc < 16 * mt + 16) { // static
                    #pragma unroll
                    for (int rg = 0; rg < 4; ++rg) {
                        int r = 16 * mt + 4 * quad + rg;
                        if (r >= 10 * cc && r < 10 * cc + 10)          // runtime
                            xm = fmaxf(xm, acc[mt][nt][rg]);
                    }
                }
            }
            xm = fmaxf(xm, __shfl_xor(xm, 16));
            xm = fmaxf(xm, __shfl_xor(xm, 32));
            float s1 = 0.f, s2 = 0.f;
            #pragma unroll
            for (int mt = 0; mt < 5; ++mt) {
                if (10 * cc + 10 > 16 * mt && 10 * cc < 16 * mt + 16) { // static
                    #pragma unroll
                    for (int rg = 0; rg < 4; ++rg) {
                        int r = 16 * mt + 4 * quad + rg;
                        if (r >= 10 * cc && r < 10 * cc + 10) {        // runtime
                            float x = acc[mt][nt][rg];
                            float e = __expf(10.0f * (x - xm));
                            s1 += e; s2 += e * x;
                        }
                    }
                }
            }
            s1 += __shfl_xor(s1, 16); s1 += __shfl_xor(s1, 32);
            s2 += __shfl_xor(s2, 16); s2 += __shfl_xor(s2, 32);
            hval[cc] = s2 / s1;
        }
        if (quad == 0) {
            float4 v0 = {hval[0], hval[1], hval[2], hval[3]};
            float4 v1 = {hval[4], hval[5], hval[6], hval[7]};
            float4* dst = (float4*)&h[(size_t)b * NCLASS + cb];
            dst[0] = v0;
            dst[1] = v1;
        }
    }
}

// ---------------- kernel 3: cross-entropy over 8192 classes per row -------
__global__ __launch_bounds__(256) void ce_kernel(
    const float* __restrict__ h, const int* __restrict__ labels,
    float* __restrict__ ce_part)
{
    __shared__ float redm[4];
    __shared__ float reds[4];
    const int b = blockIdx.x, t = threadIdx.x;
    const int wave = t >> 6, lane = t & 63;
    const int lbl = labels[b];
    const float* hb = h + (size_t)b * NCLASS;
    const float4* hb4 = (const float4*)hb;
    const int lq = lbl >> 2, lr = lbl & 3;

    float4 v[8];
    float mx = -1e30f;
    #pragma unroll
    for (int k = 0; k < 8; ++k) {
        int idx = t + k * 256;
        float4 x = hb4[idx];
        x.x = 10.0f * x.x - ((idx == lq && lr == 0) ? 0.1f : 0.0f);
        x.y = 10.0f * x.y - ((idx == lq && lr == 1) ? 0.1f : 0.0f);
        x.z = 10.0f * x.z - ((idx == lq && lr == 2) ? 0.1f : 0.0f);
        x.w = 10.0f * x.w - ((idx == lq && lr == 3) ? 0.1f : 0.0f);
        v[k] = x;
        mx = fmaxf(mx, fmaxf(fmaxf(x.x, x.y), fmaxf(x.z, x.w)));
    }
    #pragma unroll
    for (int off = 32; off; off >>= 1) mx = fmaxf(mx, __shfl_xor(mx, off));
    if (lane == 0) redm[wave] = mx;
    __syncthreads();
    mx = fmaxf(fmaxf(redm[0], redm[1]), fmaxf(redm[2], redm[3]));

    float s = 0.f;
    #pragma unroll
    for (int k = 0; k < 8; ++k) {
        s += __expf(v[k].x - mx) + __expf(v[k].y - mx)
           + __expf(v[k].z - mx) + __expf(v[k].w - mx);
    }
    #pragma unroll
    for (int off = 32; off; off >>= 1) s += __shfl_xor(s, off);
    if (lane == 0) reds[wave] = s;
    __syncthreads();
    if (t == 0) {
        s = reds[0] + reds[1] + reds[2] + reds[3];
        float logit_l = 10.0f * (hb[lbl] - 0.01f);
        ce_part[b] = mx + logf(s) - logit_l;   // -logp[label]
    }
}

// ---------------- kernel 4: reduce partials + combine ---------------------
__global__ __launch_bounds__(256) void final_kernel(
    const float* __restrict__ gram_part, const float* __restrict__ ce_part,
    float* __restrict__ out)
{
    __shared__ float red[4];
    const int t = threadIdx.x, wave = t >> 6, lane = t & 63;
    const float4* gp4 = (const float4*)gram_part;
    float g = 0.f;
    #pragma unroll
    for (int i = 0; i < 8; ++i) {
        float4 x = gp4[t + i * 256];
        g += x.x + x.y + x.z + x.w;
    }
    float val = ce_part[t] * (1.0f / 256.0f)
              + g * (0.2f / 737280.0f);       // C*K*(K-1) = 737280
    #pragma unroll
    for (int off = 32; off; off >>= 1) val += __shfl_xor(val, off);
    if (lane == 0) red[wave] = val;
    __syncthreads();
    if (t == 0) out[0] = red[0] + red[1] + red[2] + red[3];
}

extern "C" void kernel_launch(void* const* d_in, const int* in_sizes, int n_in,
                              void* d_out, int out_size, void* d_ws, size_t ws_size,
                              hipStream_t stream) {
    const float* emb    = (const float*)d_in[0];   // [256][512]
    const int*   labels = (const int*)d_in[1];     // [256]
    const float* fc     = (const float*)d_in[2];   // [81920][512]
    float* out = (float*)d_out;

    char* ws = (char*)d_ws;
    bf16*  w         = (bf16*)ws;                        //  83886080 B
    bf16*  At        = (bf16*)(ws + 83886080);           //    262144 B
    float* h         = (float*)(ws + 84148352);          //   8388608 B
    float* gram_part = (float*)(ws + 92536960);          //     32768 B
    float* ce_part   = (float*)(ws + 92569728);          //      1024 B

    prep_kernel<<<NCLASS + 64, 256, 0, stream>>>(fc, w, gram_part, emb, At);
    gemm_h_kernel<<<81920 / 80, 512, 0, stream>>>(w, At, h);
    ce_kernel<<<BATCH, 256, 0, stream>>>(h, labels, ce_part);
    final_kernel<<<1, 256, 0, stream>>>(gram_part, ce_part, out);
}